// Round 1
// baseline (161.580 us; speedup 1.0000x reference)
//
#include <hip/hip_runtime.h>

#define FIN   128
#define FOUT  128
#define KNB   32

// ---------------- Stage 1: h = x @ W (fp32) ----------------
// Block: 256 threads, 16 rows of x per block. W (64KB) + x-tile (8KB) in LDS.
// Thread t: fo = t&127, row-group rg = t>>7 (wave-uniform) -> 8 rows each.
__global__ __launch_bounds__(256) void gemm_xw(
    const float* __restrict__ x, const float* __restrict__ W,
    float* __restrict__ h, int n_rows) {
  __shared__ float Ws[FIN * FOUT];   // 64 KB
  __shared__ float xs[16 * FIN];     // 8 KB
  const int t = threadIdx.x;
  const int row_base = blockIdx.x * 16;
  const int rows_here = min(16, n_rows - row_base);

  // load W: 4096 float4, 16 per thread
  #pragma unroll
  for (int i = 0; i < 16; ++i)
    ((float4*)Ws)[i * 256 + t] = ((const float4*)W)[i * 256 + t];
  // load x tile: 512 float4, 2 per thread (guarded for tail; 50000%16==0 so never hit)
  #pragma unroll
  for (int i = 0; i < 2; ++i) {
    int e = i * 256 + t;
    if (e < rows_here * (FIN / 4))
      ((float4*)xs)[e] = ((const float4*)(x + (size_t)row_base * FIN))[e];
  }
  __syncthreads();

  const int fo = t & 127;
  const int rg = t >> 7;  // wave-uniform -> xs reads below are LDS broadcasts
  float acc[8] = {0.f,0.f,0.f,0.f,0.f,0.f,0.f,0.f};
  #pragma unroll 4
  for (int fi4 = 0; fi4 < FIN / 4; ++fi4) {
    const float w0 = Ws[(fi4 * 4 + 0) * FOUT + fo];
    const float w1 = Ws[(fi4 * 4 + 1) * FOUT + fo];
    const float w2 = Ws[(fi4 * 4 + 2) * FOUT + fo];
    const float w3 = Ws[(fi4 * 4 + 3) * FOUT + fo];
    #pragma unroll
    for (int r = 0; r < 8; ++r) {
      const float4 xq = ((const float4*)xs)[(rg * 8 + r) * (FIN / 4) + fi4];
      acc[r] += xq.x * w0;
      acc[r] += xq.y * w1;
      acc[r] += xq.z * w2;
      acc[r] += xq.w * w3;
    }
  }
  #pragma unroll
  for (int r = 0; r < 8; ++r) {
    const int row = row_base + rg * 8 + r;
    if (row < n_rows) h[(size_t)row * FOUT + fo] = acc[r];
  }
}

// ---------------- Stage 2: gather + rank-15-of-32 median ----------------
// compare-exchange on 4 independent lanes (4 features per thread)
__device__ __forceinline__ void ce4(float4& a, float4& b) {
  float4 mn, mx;
  mn.x = fminf(a.x, b.x); mx.x = fmaxf(a.x, b.x);
  mn.y = fminf(a.y, b.y); mx.y = fmaxf(a.y, b.y);
  mn.z = fminf(a.z, b.z); mx.z = fmaxf(a.z, b.z);
  mn.w = fminf(a.w, b.w); mx.w = fmaxf(a.w, b.w);
  a = mn; b = mx;
}

// Block: 256 threads = 8 nodes x 32 threads; each thread owns 4 features.
__global__ __launch_bounds__(256) void median_gather(
    const float* __restrict__ h, const int* __restrict__ nbrs,
    float* __restrict__ out, int n_nodes) {
  __shared__ int sidx[8 * KNB];
  const int t = threadIdx.x;
  const long long node_base = (long long)blockIdx.x * 8;
  // 256 ints of neighbor indices for this block's 8 nodes (coalesced)
  {
    long long g = node_base * KNB + t;
    sidx[t] = (g < (long long)n_nodes * KNB) ? nbrs[g] : 0;
  }
  __syncthreads();

  const int nl = t >> 5;            // node within block
  const int fq = (t & 31) * 4;      // first feature of this thread's quad
  const int* idx = &sidx[nl * KNB];

  // gather 32 neighbor rows: per k, 32 lanes x 16B = 512B contiguous
  float4 v[KNB];
  #pragma unroll
  for (int k = 0; k < KNB; ++k)
    v[k] = *(const float4*)(h + (size_t)idx[k] * FOUT + fq);

  // Bitonic pre-sort (kk=2..16): v[0..15] ascending, v[16..31] descending.
  #pragma unroll
  for (int kk = 2; kk <= 16; kk <<= 1) {
    #pragma unroll
    for (int j = kk >> 1; j > 0; j >>= 1) {
      #pragma unroll
      for (int i = 0; i < KNB; ++i) {
        const int l = i ^ j;
        if (l > i) {
          if ((i & kk) == 0) ce4(v[i], v[l]);   // ascending
          else               ce4(v[l], v[i]);   // descending
        }
      }
    }
  }
  // Half-cleaner: after this v[0..15] = 16 smallest (bitonic), v[16..31] = 16 largest.
  #pragma unroll
  for (int i = 0; i < 16; ++i) ce4(v[i], v[i + 16]);
  // Pruned ascending bitonic merge of lower half, keeping only deps of output 15:
  #pragma unroll
  for (int i = 0; i < 8; ++i)   ce4(v[i], v[i + 8]);    // j=8
  #pragma unroll
  for (int i = 8; i < 12; ++i)  ce4(v[i], v[i + 4]);    // j=4
  #pragma unroll
  for (int i = 12; i < 14; ++i) ce4(v[i], v[i + 2]);    // j=2
  ce4(v[14], v[15]);                                    // j=1
  // v[15] = max of the 16 smallest = rank-15 (lower median)

  const long long node = node_base + nl;
  if (node < n_nodes)
    *(float4*)(out + node * FOUT + fq) = v[15];
}

extern "C" void kernel_launch(void* const* d_in, const int* in_sizes, int n_in,
                              void* d_out, int out_size, void* d_ws, size_t ws_size,
                              hipStream_t stream) {
  const float* x    = (const float*)d_in[0];   // [N, FIN] fp32
  const int*   nbrs = (const int*)d_in[1];     // [N, K] int32
  const float* W    = (const float*)d_in[2];   // [FIN, FOUT] fp32
  float* out = (float*)d_out;                  // [N, FOUT] fp32
  float* h   = (float*)d_ws;                   // scratch: N*FOUT*4 = 25.6 MB

  const int n = in_sizes[0] / FIN;             // 50000

  gemm_xw<<<(n + 15) / 16, 256, 0, stream>>>(x, W, h, n);
  median_gather<<<(n + 7) / 8, 256, 0, stream>>>(h, nbrs, out, n);
}

// Round 2
// 87.920 us; speedup vs baseline: 1.8378x; 1.8378x over previous
//
#include <hip/hip_runtime.h>

#define FIN   128
#define FOUT  128
#define KNB   32

// ---------------- Stage 1: h(fp16) = x @ W ----------------
// Block 256 threads: 64 rows x 128 cols tile. Thread = 8 rows x 4 cols.
// x-tile in LDS (32 KB); W read from global (L2-resident, 64 KB total).
__global__ __launch_bounds__(256) void gemm_xw(
    const float* __restrict__ x, const float* __restrict__ W,
    unsigned int* __restrict__ h, int n_rows) {  // h: [n][64] packed half2
  __shared__ float xs[64 * FIN];   // 32 KB
  const int t = threadIdx.x;
  const int row_base = blockIdx.x * 64;

  // load x tile: 2048 float4, 8 per thread (guard rows for tail block)
  #pragma unroll
  for (int i = 0; i < 8; ++i) {
    const int e = i * 256 + t;       // float4 index in tile
    const int r = e >> 5;            // row within tile
    if (row_base + r < n_rows)
      ((float4*)xs)[e] = ((const float4*)(x + (size_t)row_base * FIN))[e];
  }
  __syncthreads();

  const int cg = t & 31;   // cols 4cg .. 4cg+3
  const int rg = t >> 5;   // rows 8rg .. 8rg+7   (wave-uniform)
  float acc[8][4];
  #pragma unroll
  for (int r = 0; r < 8; ++r)
    #pragma unroll
    for (int c = 0; c < 4; ++c) acc[r][c] = 0.f;

  #pragma unroll 2
  for (int fi4 = 0; fi4 < FIN / 4; ++fi4) {
    float4 w[4];   // W rows fi4*4..+3, cols 4cg..4cg+3
    #pragma unroll
    for (int q = 0; q < 4; ++q)
      w[q] = ((const float4*)W)[(fi4 * 4 + q) * (FOUT / 4) + cg];
    #pragma unroll
    for (int r = 0; r < 8; ++r) {
      const float4 xq = ((const float4*)xs)[(rg * 8 + r) * (FIN / 4) + fi4];
      #pragma unroll
      for (int c = 0; c < 4; ++c) {
        const float wc0 = (&w[0].x)[c], wc1 = (&w[1].x)[c];
        const float wc2 = (&w[2].x)[c], wc3 = (&w[3].x)[c];
        acc[r][c] += xq.x * wc0;
        acc[r][c] += xq.y * wc1;
        acc[r][c] += xq.z * wc2;
        acc[r][c] += xq.w * wc3;
      }
    }
  }

  // pack 4 fp32 -> 2x half2 (RTN via v_cvt_f16_f32) and store 8B per row
  #pragma unroll
  for (int r = 0; r < 8; ++r) {
    const int row = row_base + rg * 8 + r;
    if (row < n_rows) {
      unsigned u[4];
      #pragma unroll
      for (int c = 0; c < 4; ++c)
        asm("v_cvt_f16_f32 %0, %1" : "=v"(u[c]) : "v"(acc[r][c]));
      uint2 p;
      p.x = (u[0] & 0xffffu) | (u[1] << 16);
      p.y = (u[2] & 0xffffu) | (u[3] << 16);
      *(uint2*)(h + (size_t)row * (FOUT / 2) + cg * 2) = p;
    }
  }
}

// ---------------- Stage 2: gather + rank-15-of-32 median (packed fp16) ----
__device__ __forceinline__ void ce(unsigned& a, unsigned& b) {
  unsigned mn, mx;
  asm("v_pk_min_f16 %0, %1, %2" : "=v"(mn) : "v"(a), "v"(b));
  asm("v_pk_max_f16 %0, %1, %2" : "=v"(mx) : "v"(a), "v"(b));
  a = mn; b = mx;
}

// Block 256 = 4 nodes x 64 threads; thread owns 2 features (one packed u32).
__global__ __launch_bounds__(256) void median_gather(
    const unsigned int* __restrict__ h, const int* __restrict__ nbrs,
    float* __restrict__ out, int n_nodes) {
  __shared__ int sidx[4 * KNB];
  const int t = threadIdx.x;
  const int node_base = blockIdx.x * 4;
  if (t < 4 * KNB) {
    const int g = node_base * KNB + t;
    sidx[t] = (g < n_nodes * KNB) ? nbrs[g] : 0;
  }
  __syncthreads();

  const int nl = t >> 6;          // node within block (wave index)
  const int lane = t & 63;        // feature pair
  const int* idx = &sidx[nl * KNB];

  // gather: per k, 64 lanes x 4B = 256B contiguous from one h row
  unsigned v[KNB];
  #pragma unroll
  for (int k = 0; k < KNB; ++k)
    v[k] = h[(size_t)idx[k] * (FOUT / 2) + lane];

  // Bitonic pre-sort halves (kk=2..16)
  #pragma unroll
  for (int kk = 2; kk <= 16; kk <<= 1) {
    #pragma unroll
    for (int j = kk >> 1; j > 0; j >>= 1) {
      #pragma unroll
      for (int i = 0; i < KNB; ++i) {
        const int l = i ^ j;
        if (l > i) {
          if ((i & kk) == 0) ce(v[i], v[l]);
          else               ce(v[l], v[i]);
        }
      }
    }
  }
  // Half-cleaner: v[0..15] = 16 smallest (bitonic)
  #pragma unroll
  for (int i = 0; i < 16; ++i) ce(v[i], v[i + 16]);
  // Pruned ascending merge, deps of output 15 only
  #pragma unroll
  for (int i = 0; i < 8; ++i)   ce(v[i], v[i + 8]);
  #pragma unroll
  for (int i = 8; i < 12; ++i)  ce(v[i], v[i + 4]);
  #pragma unroll
  for (int i = 12; i < 14; ++i) ce(v[i], v[i + 2]);
  ce(v[14], v[15]);
  // v[15] = packed lower medians of the two features

  const int node = node_base + nl;
  if (node < n_nodes) {
    float flo, fhi;
    asm("v_cvt_f32_f16 %0, %1" : "=v"(flo) : "v"(v[15]));
    asm("v_cvt_f32_f16 %0, %1" : "=v"(fhi) : "v"(v[15] >> 16));
    float2 o; o.x = flo; o.y = fhi;
    *(float2*)(out + (size_t)node * FOUT + lane * 2) = o;
  }
}

extern "C" void kernel_launch(void* const* d_in, const int* in_sizes, int n_in,
                              void* d_out, int out_size, void* d_ws, size_t ws_size,
                              hipStream_t stream) {
  const float* x    = (const float*)d_in[0];   // [N, FIN] fp32
  const int*   nbrs = (const int*)d_in[1];     // [N, K] int32
  const float* W    = (const float*)d_in[2];   // [FIN, FOUT] fp32
  float* out = (float*)d_out;                  // [N, FOUT] fp32
  unsigned int* h = (unsigned int*)d_ws;       // [N, 64] packed half2 = 12.8 MB

  const int n = in_sizes[0] / FIN;             // 50000

  gemm_xw<<<(n + 63) / 64, 256, 0, stream>>>(x, W, h, n);
  median_gather<<<(n + 3) / 4, 256, 0, stream>>>(h, nbrs, out, n);
}

// Round 3
// 69.515 us; speedup vs baseline: 2.3244x; 1.2648x over previous
//
#include <hip/hip_runtime.h>

#define FIN 128
#define FOUT 128
#define KNB 32

typedef __attribute__((ext_vector_type(8))) short bf16x8;
typedef __attribute__((ext_vector_type(4))) float f32x4;

// ---- Kernel 0: stage W (fp32 [128][128]) -> bf16 A-fragments for 16x16x32 ----
// A[i][k] with i = W-col-in-tile (lane&15), k = kb*32 + (lane>>4)*8 + b.
// wf layout: [(ct*4+kb)*64 + lane] * 4 dwords (16B per lane, coalesced loads).
__global__ __launch_bounds__(256) void wf_stage(
    const float* __restrict__ W, unsigned* __restrict__ wf) {
  const int id = blockIdx.x * 256 + threadIdx.x;   // 0..2047
  if (id >= 2048) return;
  const int lane = id & 63;
  const int kb = (id >> 6) & 3;
  const int ct = id >> 8;
  const int krow = kb * 32 + (lane >> 4) * 8;
  const int col = ct * 16 + (lane & 15);
  unsigned d[4];
  #pragma unroll
  for (int p = 0; p < 4; ++p) {
    const float lo = W[(krow + 2 * p) * FOUT + col];
    const float hi = W[(krow + 2 * p + 1) * FOUT + col];
    asm("v_cvt_pk_bf16_f32 %0, %1, %2" : "=v"(d[p]) : "v"(lo), "v"(hi));
  }
  uint4 q; q.x = d[0]; q.y = d[1]; q.z = d[2]; q.w = d[3];
  *(uint4*)(wf + (size_t)id * 4) = q;
}

// ---- Kernel 1: h(fp16) = x @ W via bf16 MFMA ----
// Per wave: 16 x-rows (j = lane&15) x 128 cols. D = A(Wf) * B(x):
// D[i][j]: j = lane&15 = x-row, i = (lane>>4)*4 + b = col-in-tile.
__global__ __launch_bounds__(256) void gemm_mfma(
    const float* __restrict__ x, const unsigned* __restrict__ wf,
    unsigned* __restrict__ h, int n_rows) {     // h as dwords [n][64] (fp16 pairs)
  const int t = threadIdx.x;
  const int wv = t >> 6;
  const int l = t & 63;
  const int row = blockIdx.x * 64 + wv * 16 + (l & 15);
  const int rsafe = min(row, n_rows - 1);
  const int kq = l >> 4;   // 0..3

  // load & convert this lane's x fragment: B[k][j], k = kb*32 + kq*8 + e
  bf16x8 xf[4];
  #pragma unroll
  for (int kb = 0; kb < 4; ++kb) {
    const float* xp = x + (size_t)rsafe * FIN + kb * 32 + kq * 8;
    const float4 x0 = *(const float4*)(xp);
    const float4 x1 = *(const float4*)(xp + 4);
    union { unsigned u[4]; bf16x8 v; } pk;
    asm("v_cvt_pk_bf16_f32 %0, %1, %2" : "=v"(pk.u[0]) : "v"(x0.x), "v"(x0.y));
    asm("v_cvt_pk_bf16_f32 %0, %1, %2" : "=v"(pk.u[1]) : "v"(x0.z), "v"(x0.w));
    asm("v_cvt_pk_bf16_f32 %0, %1, %2" : "=v"(pk.u[2]) : "v"(x1.x), "v"(x1.y));
    asm("v_cvt_pk_bf16_f32 %0, %1, %2" : "=v"(pk.u[3]) : "v"(x1.z), "v"(x1.w));
    xf[kb] = pk.v;
  }

  #pragma unroll
  for (int ct = 0; ct < 8; ++ct) {
    f32x4 acc = {0.f, 0.f, 0.f, 0.f};
    #pragma unroll
    for (int kb = 0; kb < 4; ++kb) {
      union { uint4 q; bf16x8 v; } af;
      af.q = *(const uint4*)(wf + (size_t)((ct * 4 + kb) * 64 + l) * 4);
      acc = __builtin_amdgcn_mfma_f32_16x16x32_bf16(af.v, xf[kb], acc, 0, 0, 0);
    }
    if (row < n_rows) {
      unsigned p0, p1;   // cols ct*16 + kq*4 + {0,1} and {2,3}
      asm("v_cvt_pkrtz_f16_f32 %0, %1, %2" : "=v"(p0) : "v"(acc[0]), "v"(acc[1]));
      asm("v_cvt_pkrtz_f16_f32 %0, %1, %2" : "=v"(p1) : "v"(acc[2]), "v"(acc[3]));
      uint2 st; st.x = p0; st.y = p1;
      *(uint2*)(h + (size_t)row * 64 + ct * 8 + kq * 2) = st;
    }
  }
}

// ---- Kernel 2: gather + rank-15-of-32 median (packed fp16) ----
__device__ __forceinline__ void ce(unsigned& a, unsigned& b) {
  unsigned mn, mx;
  asm("v_pk_min_f16 %0, %1, %2" : "=v"(mn) : "v"(a), "v"(b));
  asm("v_pk_max_f16 %0, %1, %2" : "=v"(mx) : "v"(a), "v"(b));
  a = mn; b = mx;
}

// Batcher odd-even mergesort of v[base..base+15] (63 CEs, fully unrolled)
#define OEMS16(v, base)                                                        \
  _Pragma("unroll") for (int p = 1; p < 16; p <<= 1)                           \
  _Pragma("unroll") for (int k = p; k >= 1; k >>= 1)                           \
  _Pragma("unroll") for (int j = k & (p - 1); j + k < 16; j += 2 * k)          \
  _Pragma("unroll") for (int i = 0; i < k; ++i)                                \
    if (((i + j) / (2 * p)) == ((i + j + k) / (2 * p)))                        \
      ce(v[(base) + i + j], v[(base) + i + j + k]);

// Block 256 = 4 nodes x 1 wave; thread owns 2 features (one packed dword).
__global__ __launch_bounds__(256) void median_gather(
    const unsigned* __restrict__ h, const int* __restrict__ nbrs,
    float* __restrict__ out, int n_nodes) {
  const int t = threadIdx.x;
  const int lane = t & 63;
  const int node = __builtin_amdgcn_readfirstlane(blockIdx.x * 4 + (t >> 6));
  const int* __restrict__ idx = nbrs + node * KNB;   // wave-uniform -> s_load

  // gather: per k, 64 lanes x 4B = 256B contiguous from one h row
  unsigned v[KNB];
  #pragma unroll
  for (int k = 0; k < KNB; ++k)
    v[k] = h[(unsigned)idx[k] * 64u + (unsigned)lane];

  // sort the two halves ascending
  OEMS16(v, 0)
  OEMS16(v, 16)

  // rank-15 of the union of two sorted 16-seqs: max_i min(a[i], b[15-i])
  unsigned m[16];
  #pragma unroll
  for (int i = 0; i < 16; ++i)
    asm("v_pk_min_f16 %0, %1, %2" : "=v"(m[i]) : "v"(v[i]), "v"(v[16 + 15 - i]));
  #pragma unroll
  for (int s = 8; s >= 1; s >>= 1)
    #pragma unroll
    for (int i = 0; i < s; ++i)
      asm("v_pk_max_f16 %0, %1, %2" : "=v"(m[i]) : "v"(m[i]), "v"(m[i + s]));

  // unpack m[0] (two fp16 medians) -> fp32 pair
  float flo, fhi;
  asm("v_cvt_f32_f16 %0, %1" : "=v"(flo) : "v"(m[0]));
  asm("v_cvt_f32_f16 %0, %1" : "=v"(fhi) : "v"(m[0] >> 16));
  float2 o; o.x = flo; o.y = fhi;
  *(float2*)(out + (size_t)node * FOUT + lane * 2) = o;
}

extern "C" void kernel_launch(void* const* d_in, const int* in_sizes, int n_in,
                              void* d_out, int out_size, void* d_ws, size_t ws_size,
                              hipStream_t stream) {
  const float* x    = (const float*)d_in[0];   // [N, FIN] fp32
  const int*   nbrs = (const int*)d_in[1];     // [N, K] int32
  const float* W    = (const float*)d_in[2];   // [FIN, FOUT] fp32
  float* out = (float*)d_out;                  // [N, FOUT] fp32

  unsigned* h  = (unsigned*)d_ws;                    // [N][64] fp16-pairs, 12.8 MB
  unsigned* wf = (unsigned*)d_ws + 3200000;          // 32 KB W fragments

  const int n = in_sizes[0] / FIN;             // 50000

  wf_stage<<<8, 256, 0, stream>>>(W, wf);
  gemm_mfma<<<(n + 63) / 64, 256, 0, stream>>>(x, wf, h, n);
  median_gather<<<n / 4, 256, 0, stream>>>(h, nbrs, out, n);
}